// Round 1
// 422.366 us; speedup vs baseline: 1.2465x; 1.2465x over previous
//
#include <hip/hip_runtime.h>
#include <stdint.h>

typedef unsigned short u16;
typedef unsigned int   u32;

typedef short s8v __attribute__((ext_vector_type(8)));
typedef short s4v __attribute__((ext_vector_type(4)));
typedef float f4v __attribute__((ext_vector_type(4)));

struct __align__(8) US4 { u16 x, y, z, w; };

__device__ __forceinline__ u16 f2bf(float f) {
    union { float f; u32 u; } v; v.f = f;
    u32 u = v.u;
    return (u16)((u + 0x7fffu + ((u >> 16) & 1u)) >> 16);
}

// 16x16x16 bf16 MFMA (gfx90a+, valid on gfx950)
#define MFMA16(a, b, c) __builtin_amdgcn_mfma_f32_16x16x16bf16_1k((a), (b), (c), 0, 0, 0)
// 16x16x32 bf16 MFMA (gfx950)
#define MFMA32(a, b, c) __builtin_amdgcn_mfma_f32_16x16x32_bf16((a), (b), (c), 0, 0, 0)

// ---------------------------------------------------------------------------
// Pack kernel (unchanged): weights -> bf16 MFMA A-fragment order; bias -> C-frag
// ---------------------------------------------------------------------------
__global__ void pack_kernel(const float* __restrict__ qkv_w, const float* __restrict__ proj_w,
                            const float* __restrict__ table, const int* __restrict__ ridx,
                            u16* __restrict__ pkQ, u16* __restrict__ pkP, float* __restrict__ biasP)
{
    int tid = blockIdx.x * 256 + threadIdx.x;
    if (tid < 24576) {
        int g = tid;
        int lane = g & 63, ks = (g >> 6) & 7, mt = g >> 9;
        int quad = lane >> 4, c = lane & 15;
        union { u16 h[8]; s8v v; } tmp;
#pragma unroll
        for (int j = 0; j < 8; ++j) {
            int kk = ks * 32 + quad * 8 + j;
            tmp.h[j] = f2bf(qkv_w[kk * 768 + mt * 16 + c]);
        }
        *(s8v*)&pkQ[g * 8] = tmp.v;
    } else if (tid < 32768) {
        int g = tid - 24576;
        int lane = g & 63, ks = (g >> 6) & 7, mt = g >> 9;
        int quad = lane >> 4, c = lane & 15;
        union { u16 h[8]; s8v v; } tmp;
#pragma unroll
        for (int j = 0; j < 8; ++j) {
            int kk = ks * 32 + quad * 8 + j;
            tmp.h[j] = f2bf(proj_w[kk * 256 + mt * 16 + c]);
        }
        *(s8v*)&pkP[g * 8] = tmp.v;
    } else if (tid < 49152) {
        int g = tid - 32768;
        int h = g >> 10, rest = (g >> 6) & 15, lane = g & 63;
        int mt = rest >> 2, nt = rest & 3;
        int quad = lane >> 4, c = lane & 15;
        int query = nt * 16 + c;
#pragma unroll
        for (int r = 0; r < 4; ++r) {
            int key = mt * 16 + quad * 4 + r;
            biasP[g * 4 + r] = table[ridx[query * 64 + key] * 16 + h];
        }
    }
}

// ---------------------------------------------------------------------------
// Main fused kernel: one block per 8x8 window. 512 threads = 8 waves, 2 heads/wave.
// LDS = 75,264 B  ->  2 blocks/CU.  Frag-identity: q/k never touch LDS.
// ---------------------------------------------------------------------------
__global__ __launch_bounds__(512, 4)
void attn_win_kernel(const float* __restrict__ X,
                     const float* __restrict__ pre_g, const float* __restrict__ pre_b,
                     const float* __restrict__ post_g, const float* __restrict__ post_b,
                     const float* __restrict__ qkv_b, const float* __restrict__ proj_b,
                     const u16* __restrict__ pkQ, const u16* __restrict__ pkP,
                     const float* __restrict__ biasP,
                     float* __restrict__ out)
{
    // LDS carve-out (75,264 B total):
    //   [     0, 33792) xnS [64][264] bf16 token-major (xn; later attnout)
    //   [ 33792, 70656) vS  [256][72] bf16 channel-major (v^T)
    //   xf (fp32 [256][68] = 69,632 B) aliases xnS+vS in the epilogue only
    //   [ 70656, 74752) pst [8][64][2] fp32 per-wave LN partials
    //   [ 74752, 75264) st  [64][2]    fp32 LN stats
    __shared__ __align__(16) unsigned char smem[75264];
    u16*   xnS = (u16*)smem;
    u16*   vS  = (u16*)(smem + 33792);
    float* xf  = (float*)smem;
    float* pst = (float*)(smem + 70656);
    float* st  = (float*)(smem + 74752);

    const int tid  = threadIdx.x;
    const int w    = tid >> 6;    // wave id 0..7
    const int l    = tid & 63;    // lane
    const int quad = l >> 4;
    const int cc   = l & 15;

    // XCD-contiguous window remap: each XCD gets 256 consecutive windows
    const int bidx = blockIdx.x;
    const int win  = ((bidx & 7) << 8) | (bidx >> 3);
    const int bb = win >> 10;
    const int wh = (win >> 5) & 31;
    const int ww = win & 31;
    const size_t base = (((size_t)bb * 256) * 256 + wh * 8) * 256 + ww * 8;

    const int ch0 = tid >> 4;          // 0..31
    const int t0  = (tid & 15) * 4;    // token group
    const int r0  = t0 >> 3, c0 = t0 & 7;

    // ---- phase 0a: coalesced window load into registers (channel-major) ----
    f4v xv[8];
#pragma unroll
    for (int it = 0; it < 8; ++it) {
        int ch = it * 32 + ch0;
        xv[it] = *(const f4v*)(X + base + (size_t)ch * 65536 + r0 * 256 + c0);
    }

    // ---- phase 0b: pre-LN stats from registers (quad-shfl + cross-wave LDS) ----
    {
        float s[4] = {0.f,0.f,0.f,0.f}, ss[4] = {0.f,0.f,0.f,0.f};
#pragma unroll
        for (int it = 0; it < 8; ++it)
#pragma unroll
            for (int j = 0; j < 4; ++j) { float x = xv[it][j]; s[j] += x; ss[j] += x * x; }
#pragma unroll
        for (int j = 0; j < 4; ++j) {
            s[j]  += __shfl_xor(s[j], 16, 64);  s[j]  += __shfl_xor(s[j], 32, 64);
            ss[j] += __shfl_xor(ss[j], 16, 64); ss[j] += __shfl_xor(ss[j], 32, 64);
        }
        if (quad == 0) {
#pragma unroll
            for (int j = 0; j < 4; ++j) {
                pst[(w * 64 + t0 + j) * 2]     = s[j];
                pst[(w * 64 + t0 + j) * 2 + 1] = ss[j];
            }
        }
    }
    __syncthreads();
    if (tid < 64) {
        float S = 0.f, SS = 0.f;
#pragma unroll
        for (int wv = 0; wv < 8; ++wv) {
            S  += pst[(wv * 64 + tid) * 2];
            SS += pst[(wv * 64 + tid) * 2 + 1];
        }
        float mean = S * (1.f / 256.f);
        float var  = SS * (1.f / 256.f) - mean * mean;
        st[tid * 2] = mean; st[tid * 2 + 1] = rsqrtf(var + 1e-5f);
    }
    __syncthreads();

    // ---- phase 0c: xn = LN(x)*g+b -> bf16 token-major (channel-pair packed b32) ----
    {
        float mean[4], rstd[4];
#pragma unroll
        for (int j = 0; j < 4; ++j) { mean[j] = st[(t0 + j) * 2]; rstd[j] = st[(t0 + j) * 2 + 1]; }
#pragma unroll
        for (int it = 0; it < 8; ++it) {
            int ch = it * 32 + ch0;
            float g = pre_g[ch], b = pre_b[ch];
            u16 m0 = f2bf((xv[it][0] - mean[0]) * rstd[0] * g + b);
            u16 m1 = f2bf((xv[it][1] - mean[1]) * rstd[1] * g + b);
            u16 m2 = f2bf((xv[it][2] - mean[2]) * rstd[2] * g + b);
            u16 m3 = f2bf((xv[it][3] - mean[3]) * rstd[3] * g + b);
            u32 m01 = (u32)m0 | ((u32)m1 << 16);
            u32 m23 = (u32)m2 | ((u32)m3 << 16);
            u32 p01 = __shfl_xor(m01, 16, 64);   // partner holds ch^1
            u32 p23 = __shfl_xor(m23, 16, 64);
            if ((quad & 1) == 0) {
                // even ch: tokens t0, t0+1; low = own(ch), high = partner(ch+1)
                *(u32*)&xnS[(t0 + 0) * 264 + ch] = (m01 & 0xffffu) | ((p01 & 0xffffu) << 16);
                *(u32*)&xnS[(t0 + 1) * 264 + ch] = (m01 >> 16)    | (p01 & 0xffff0000u);
            } else {
                // odd ch: tokens t0+2, t0+3; low = partner(ch-1), high = own(ch)
                *(u32*)&xnS[(t0 + 2) * 264 + ch - 1] = (p23 & 0xffffu) | ((m23 & 0xffffu) << 16);
                *(u32*)&xnS[(t0 + 3) * 264 + ch - 1] = (p23 >> 16)    | (m23 & 0xffff0000u);
            }
        }
    }
    __syncthreads();

    // ---- phases 1+2 fused per head: barrier-free stretch ----
    // Wave w owns heads 2w, 2w+1. QKV m-tiles {h, 16+h, 32+h}: the C-fragments of
    // q/k ARE the A/B fragments attention needs (row=4q+r <-> k=4q+j identity),
    // so q/k stay in registers; only v goes through LDS (transpose).
    US4 outbuf[2][4];
    const s8v* AQ = (const s8v*)pkQ;
#pragma unroll
    for (int hi = 0; hi < 2; ++hi) {
        const int head = w * 2 + hi;
        s4v qfr[4], kfr[4];
        {
            f4v acc0[4], acc1[4], acc2[4];
#pragma unroll
            for (int nt = 0; nt < 4; ++nt) { acc0[nt] = 0.f; acc1[nt] = 0.f; acc2[nt] = 0.f; }
#pragma unroll
            for (int ks = 0; ks < 8; ++ks) {
                s8v bfr[4];
#pragma unroll
                for (int nt = 0; nt < 4; ++nt)
                    bfr[nt] = *(const s8v*)&xnS[(nt * 16 + cc) * 264 + ks * 32 + quad * 8];
                s8v a0 = AQ[((head     ) * 8 + ks) * 64 + l];
                s8v a1 = AQ[((head + 16) * 8 + ks) * 64 + l];
                s8v a2 = AQ[((head + 32) * 8 + ks) * 64 + l];
#pragma unroll
                for (int nt = 0; nt < 4; ++nt) {
                    acc0[nt] = MFMA32(a0, bfr[nt], acc0[nt]);
                    acc1[nt] = MFMA32(a1, bfr[nt], acc1[nt]);
                    acc2[nt] = MFMA32(a2, bfr[nt], acc2[nt]);
                }
            }
            // q epilogue: bias + l2norm -> qfr (registers)
            {
                float b0 = qkv_b[head * 16 + quad * 4 + 0];
                float b1 = qkv_b[head * 16 + quad * 4 + 1];
                float b2 = qkv_b[head * 16 + quad * 4 + 2];
                float b3 = qkv_b[head * 16 + quad * 4 + 3];
#pragma unroll
                for (int nt = 0; nt < 4; ++nt) {
                    f4v a = acc0[nt];
                    a[0] += b0; a[1] += b1; a[2] += b2; a[3] += b3;
                    float sq = a[0]*a[0] + a[1]*a[1] + a[2]*a[2] + a[3]*a[3];
                    sq += __shfl_xor(sq, 16, 64);
                    sq += __shfl_xor(sq, 32, 64);
                    float inv = 1.0f / fmaxf(sqrtf(sq), 1e-12f);
                    s4v f;
                    f[0] = (short)f2bf(a[0] * inv); f[1] = (short)f2bf(a[1] * inv);
                    f[2] = (short)f2bf(a[2] * inv); f[3] = (short)f2bf(a[3] * inv);
                    qfr[nt] = f;
                }
            }
            // k epilogue: bias + l2norm -> kfr (registers)
            {
                float b0 = qkv_b[(head + 16) * 16 + quad * 4 + 0];
                float b1 = qkv_b[(head + 16) * 16 + quad * 4 + 1];
                float b2 = qkv_b[(head + 16) * 16 + quad * 4 + 2];
                float b3 = qkv_b[(head + 16) * 16 + quad * 4 + 3];
#pragma unroll
                for (int nt = 0; nt < 4; ++nt) {
                    f4v a = acc1[nt];
                    a[0] += b0; a[1] += b1; a[2] += b2; a[3] += b3;
                    float sq = a[0]*a[0] + a[1]*a[1] + a[2]*a[2] + a[3]*a[3];
                    sq += __shfl_xor(sq, 16, 64);
                    sq += __shfl_xor(sq, 32, 64);
                    float inv = 1.0f / fmaxf(sqrtf(sq), 1e-12f);
                    s4v f;
                    f[0] = (short)f2bf(a[0] * inv); f[1] = (short)f2bf(a[1] * inv);
                    f[2] = (short)f2bf(a[2] * inv); f[3] = (short)f2bf(a[3] * inv);
                    kfr[nt] = f;
                }
            }
            // v epilogue: bias + pair-swap transpose-store to vS (this wave's rows only)
            {
                float b0 = qkv_b[(head + 32) * 16 + quad * 4 + 0];
                float b1 = qkv_b[(head + 32) * 16 + quad * 4 + 1];
                float b2 = qkv_b[(head + 32) * 16 + quad * 4 + 2];
                float b3 = qkv_b[(head + 32) * 16 + quad * 4 + 3];
                int chb = head * 16 + quad * 4;
#pragma unroll
                for (int nt = 0; nt < 4; ++nt) {
                    f4v a = acc2[nt];
                    a[0] += b0; a[1] += b1; a[2] += b2; a[3] += b3;
                    int tok = nt * 16 + cc;
                    float p0 = __shfl_xor(a[0], 1, 64), p1 = __shfl_xor(a[1], 1, 64);
                    float p2 = __shfl_xor(a[2], 1, 64), p3 = __shfl_xor(a[3], 1, 64);
                    if ((l & 1) == 0) {
                        *(u32*)&vS[(chb + 0) * 72 + tok] = (u32)f2bf(a[0]) | ((u32)f2bf(p0) << 16);
                        *(u32*)&vS[(chb + 1) * 72 + tok] = (u32)f2bf(a[1]) | ((u32)f2bf(p1) << 16);
                    } else {
                        *(u32*)&vS[(chb + 2) * 72 + tok - 1] = (u32)f2bf(p2) | ((u32)f2bf(a[2]) << 16);
                        *(u32*)&vS[(chb + 3) * 72 + tok - 1] = (u32)f2bf(p3) | ((u32)f2bf(a[3]) << 16);
                    }
                }
            }
        }
        // attention for this head (q/k frags from registers, v from own-wave LDS)
        {
            s4v vfr[4];
#pragma unroll
            for (int kt = 0; kt < 4; ++kt)
                vfr[kt] = *(const s4v*)&vS[(head * 16 + cc) * 72 + kt * 16 + quad * 4];
            const f4v* BP = (const f4v*)biasP;
#pragma unroll
            for (int half = 0; half < 2; ++half) {
                f4v sT[4][2];
#pragma unroll
                for (int nt2 = 0; nt2 < 2; ++nt2) {
                    int nt = half * 2 + nt2;
#pragma unroll
                    for (int mt = 0; mt < 4; ++mt)
                        sT[mt][nt2] = MFMA16(kfr[mt], qfr[nt], BP[(head * 16 + mt * 4 + nt) * 64 + l]);
                }
#pragma unroll
                for (int nt2 = 0; nt2 < 2; ++nt2) {
                    int nt = half * 2 + nt2;
                    float mx = -1e30f;
#pragma unroll
                    for (int mt = 0; mt < 4; ++mt)
#pragma unroll
                        for (int r = 0; r < 4; ++r) mx = fmaxf(mx, sT[mt][nt2][r]);
                    mx = fmaxf(mx, __shfl_xor(mx, 16, 64));
                    mx = fmaxf(mx, __shfl_xor(mx, 32, 64));
                    float p[16];
                    float sum = 0.f;
#pragma unroll
                    for (int mt = 0; mt < 4; ++mt)
#pragma unroll
                        for (int r = 0; r < 4; ++r) {
                            float e = __expf(sT[mt][nt2][r] - mx);
                            p[mt * 4 + r] = e; sum += e;
                        }
                    sum += __shfl_xor(sum, 16, 64);
                    sum += __shfl_xor(sum, 32, 64);
                    float inv = 1.f / sum;
                    f4v o = 0.f;
#pragma unroll
                    for (int kt = 0; kt < 4; ++kt) {
                        s4v pv = { (short)f2bf(p[kt * 4 + 0] * inv), (short)f2bf(p[kt * 4 + 1] * inv),
                                   (short)f2bf(p[kt * 4 + 2] * inv), (short)f2bf(p[kt * 4 + 3] * inv) };
                        o = MFMA16(vfr[kt], pv, o);   // out^T[d][query] += v^T . P^T
                    }
                    US4 ov; ov.x = f2bf(o[0]); ov.y = f2bf(o[1]); ov.z = f2bf(o[2]); ov.w = f2bf(o[3]);
                    outbuf[hi][nt] = ov;              // buffered; xnS still being read by others
                }
            }
        }
    }
    __syncthreads();   // all phase-1 xnS reads complete
#pragma unroll
    for (int hi = 0; hi < 2; ++hi)
#pragma unroll
        for (int nt = 0; nt < 4; ++nt)
            *(US4*)&xnS[(nt * 16 + cc) * 264 + (w * 2 + hi) * 16 + quad * 4] = outbuf[hi][nt];
    __syncthreads();

    // ---- phase 3: proj^T GEMM (wave w -> m-tiles 2w, 2w+1); prefetch X for residual ----
    f4v xv2[8];
#pragma unroll
    for (int it = 0; it < 8; ++it) {
        int ch = it * 32 + ch0;
        xv2[it] = *(const f4v*)(X + base + (size_t)ch * 65536 + r0 * 256 + c0);
    }
    f4v pa0[4], pa1[4];
#pragma unroll
    for (int nt = 0; nt < 4; ++nt) { pa0[nt] = 0.f; pa1[nt] = 0.f; }
    {
        const s8v* AP = (const s8v*)pkP;
#pragma unroll
        for (int ks = 0; ks < 8; ++ks) {
            s8v bfr[4];
#pragma unroll
            for (int nt = 0; nt < 4; ++nt)
                bfr[nt] = *(const s8v*)&xnS[(nt * 16 + cc) * 264 + ks * 32 + quad * 8];
            s8v a0 = AP[((w * 2    ) * 8 + ks) * 64 + l];
            s8v a1 = AP[((w * 2 + 1) * 8 + ks) * 64 + l];
#pragma unroll
            for (int nt = 0; nt < 4; ++nt) {
                pa0[nt] = MFMA32(a0, bfr[nt], pa0[nt]);
                pa1[nt] = MFMA32(a1, bfr[nt], pa1[nt]);
            }
        }
    }
    __syncthreads();   // xnS dead everywhere; xf (alias) may now be written
    {
        int chb0 = (w * 2    ) * 16 + quad * 4;
        int chb1 = (w * 2 + 1) * 16 + quad * 4;
        float c00 = proj_b[chb0 + 0], c01 = proj_b[chb0 + 1], c02 = proj_b[chb0 + 2], c03 = proj_b[chb0 + 3];
        float c10 = proj_b[chb1 + 0], c11 = proj_b[chb1 + 1], c12 = proj_b[chb1 + 2], c13 = proj_b[chb1 + 3];
#pragma unroll
        for (int nt = 0; nt < 4; ++nt) {
            int tok = nt * 16 + cc;
            xf[(chb0 + 0) * 68 + tok] = pa0[nt][0] + c00;
            xf[(chb0 + 1) * 68 + tok] = pa0[nt][1] + c01;
            xf[(chb0 + 2) * 68 + tok] = pa0[nt][2] + c02;
            xf[(chb0 + 3) * 68 + tok] = pa0[nt][3] + c03;
            xf[(chb1 + 0) * 68 + tok] = pa1[nt][0] + c10;
            xf[(chb1 + 1) * 68 + tok] = pa1[nt][1] + c11;
            xf[(chb1 + 2) * 68 + tok] = pa1[nt][2] + c12;
            xf[(chb1 + 3) * 68 + tok] = pa1[nt][3] + c13;
        }
    }
    __syncthreads();

    // ---- phase 4: residual add (X re-read, L3-resident) + post-LN stats ----
    f4v yv[8];
    {
        float s[4] = {0.f,0.f,0.f,0.f}, ss[4] = {0.f,0.f,0.f,0.f};
#pragma unroll
        for (int it = 0; it < 8; ++it) {
            int ch = it * 32 + ch0;
            f4v o = *(const f4v*)&xf[ch * 68 + t0];
            f4v y = xv2[it] + o;
            yv[it] = y;
#pragma unroll
            for (int j = 0; j < 4; ++j) { s[j] += y[j]; ss[j] += y[j] * y[j]; }
        }
#pragma unroll
        for (int j = 0; j < 4; ++j) {
            s[j]  += __shfl_xor(s[j], 16, 64);  s[j]  += __shfl_xor(s[j], 32, 64);
            ss[j] += __shfl_xor(ss[j], 16, 64); ss[j] += __shfl_xor(ss[j], 32, 64);
        }
        if (quad == 0) {
#pragma unroll
            for (int j = 0; j < 4; ++j) {
                pst[(w * 64 + t0 + j) * 2]     = s[j];
                pst[(w * 64 + t0 + j) * 2 + 1] = ss[j];
            }
        }
    }
    __syncthreads();
    if (tid < 64) {
        float S = 0.f, SS = 0.f;
#pragma unroll
        for (int wv = 0; wv < 8; ++wv) {
            S  += pst[(wv * 64 + tid) * 2];
            SS += pst[(wv * 64 + tid) * 2 + 1];
        }
        float mean = S * (1.f / 256.f);
        float var  = SS * (1.f / 256.f) - mean * mean;
        st[tid * 2] = mean; st[tid * 2 + 1] = rsqrtf(var + 1e-5f);
    }
    __syncthreads();

    // ---- phase 5: y + LN(y)*g+b, coalesced store ----
    {
        float mean[4], rstd[4];
#pragma unroll
        for (int j = 0; j < 4; ++j) { mean[j] = st[(t0 + j) * 2]; rstd[j] = st[(t0 + j) * 2 + 1]; }
#pragma unroll
        for (int it = 0; it < 8; ++it) {
            int ch = it * 32 + ch0;
            float g = post_g[ch], b = post_b[ch];
            f4v y = yv[it], z;
#pragma unroll
            for (int j = 0; j < 4; ++j)
                z[j] = y[j] + (y[j] - mean[j]) * rstd[j] * g + b;
            *(f4v*)(out + base + (size_t)ch * 65536 + r0 * 256 + c0) = z;
        }
    }
}

extern "C" void kernel_launch(void* const* d_in, const int* in_sizes, int n_in,
                              void* d_out, int out_size, void* d_ws, size_t ws_size,
                              hipStream_t stream)
{
    const float* X      = (const float*)d_in[0];
    const float* pre_g  = (const float*)d_in[1];
    const float* pre_b  = (const float*)d_in[2];
    const float* post_g = (const float*)d_in[3];
    const float* post_b = (const float*)d_in[4];
    const float* qkv_w  = (const float*)d_in[5];
    const float* qkv_b  = (const float*)d_in[6];
    const float* proj_w = (const float*)d_in[7];
    const float* proj_b = (const float*)d_in[8];
    const float* table  = (const float*)d_in[9];
    const int*   ridx   = (const int*)d_in[10];

    u16*   pkQ   = (u16*)d_ws;                          // 393,216 B
    u16*   pkP   = (u16*)((char*)d_ws + 393216);        // 131,072 B
    float* biasP = (float*)((char*)d_ws + 524288);      // 262,144 B

    pack_kernel<<<192, 256, 0, stream>>>(qkv_w, proj_w, table, ridx, pkQ, pkP, biasP);
    attn_win_kernel<<<2048, 512, 0, stream>>>(X, pre_g, pre_b, post_g, post_b,
                                              qkv_b, proj_b, pkQ, pkP, biasP,
                                              (float*)d_out);
}